// Round 1
// baseline (441.490 us; speedup 1.0000x reference)
//
#include <hip/hip_runtime.h>

#define HDIM 64

// 16-lane butterfly sum (subgroup-local: masks 1,2,4,8 stay in bits 0-3).
__device__ __forceinline__ float sub16_sum(float v) {
  v += __shfl_xor(v, 1);
  v += __shfl_xor(v, 2);
  v += __shfl_xor(v, 4);
  v += __shfl_xor(v, 8);
  return v;
}

__device__ __forceinline__ int wave_sum_i(int v) {
  v += __shfl_xor(v, 1);
  v += __shfl_xor(v, 2);
  v += __shfl_xor(v, 4);
  v += __shfl_xor(v, 8);
  v += __shfl_xor(v, 16);
  v += __shfl_xor(v, 32);
  return v;
}

// ---------------------------------------------------------------------------
// Scan pass 1: per-block (256 groups) intra-block exclusive prefix of
// size[]/target_size[] plus per-block totals.
// ---------------------------------------------------------------------------
__global__ __launch_bounds__(256) void scan_blocks(
    const int* __restrict__ size, const int* __restrict__ tsize, int B,
    int* __restrict__ seg_loc, int* __restrict__ tgt_loc,
    int* __restrict__ seg_tot, int* __restrict__ tgt_tot) {
  __shared__ int s1[256];
  __shared__ int s2[256];
  const int t = threadIdx.x;
  const int i = blockIdx.x * 256 + t;
  const int a = (i < B) ? size[i] : 0;
  const int b = (i < B) ? tsize[i] : 0;
  s1[t] = a; s2[t] = b;
  __syncthreads();
#pragma unroll
  for (int d = 1; d < 256; d <<= 1) {
    const int v1 = (t >= d) ? s1[t - d] : 0;
    const int v2 = (t >= d) ? s2[t - d] : 0;
    __syncthreads();
    s1[t] += v1; s2[t] += v2;
    __syncthreads();
  }
  if (i < B) { seg_loc[i] = s1[t] - a; tgt_loc[i] = s2[t] - b; }
  if (t == 255) { seg_tot[blockIdx.x] = s1[255]; tgt_tot[blockIdx.x] = s2[255]; }
}

// ---------------------------------------------------------------------------
// Scan pass 2: add the cross-block base to every group's local prefix so
// seg_loc/tgt_loc hold FINAL global offsets. Each of the (<=64) blocks does a
// redundant masked wave-reduce over the tiny L2-hot totals array (4 waves do
// it independently to avoid shared-mem sync). This hoists the base reduce out
// of all 16384 hot-kernel waves.
// ---------------------------------------------------------------------------
__global__ __launch_bounds__(256) void finalize_scan(
    int* __restrict__ seg_loc, int* __restrict__ tgt_loc,
    const int* __restrict__ seg_tot, const int* __restrict__ tgt_tot,
    int nb, int B) {
  const int bid = blockIdx.x;
  const int lane = threadIdx.x & 63;
  int b1 = 0, b2 = 0;
  for (int s = 0; s < nb; s += 64) {
    const int i = s + lane;
    const bool m = (i < nb) & (i < bid);
    b1 += wave_sum_i(m ? seg_tot[i] : 0);
    b2 += wave_sum_i(m ? tgt_tot[i] : 0);
  }
  const int g = bid * 256 + threadIdx.x;
  if (g < B) { seg_loc[g] += b1; tgt_loc[g] += b2; }
}

// ---------------------------------------------------------------------------
// One wave per group. sub = lane>>4 picks a row slot (4 rows per load pass),
// c4 = lane&15 picks the float4 column quad: each global_load_dwordx4 moves
// 4 full embedding rows (1 KB) coalesced. Fast path (sz<=64, tn<=16) is
// branch-free: clamped indices + 0/1 weights so ALL gathers issue up-front.
// __launch_bounds__(256,3): guarantee >=12 waves/CU for gather latency hiding.
// ---------------------------------------------------------------------------
__global__ __launch_bounds__(256, 3) void simplex_kernel(
    const int* __restrict__ user, const int* __restrict__ item,
    const int* __restrict__ target_item, const int* __restrict__ size,
    const int* __restrict__ tsize, const float* __restrict__ uw,
    const float* __restrict__ iw, const int* __restrict__ seg_loc,
    const int* __restrict__ tgt_loc, float* __restrict__ out, int B,
    int useg, int utgt) {
  const int g = (int)((blockIdx.x * blockDim.x + threadIdx.x) >> 6);
  if (g >= B) return;
  const int lane = threadIdx.x & 63;
  const int sub = lane >> 4;
  const int c4 = lane & 15;

  const int sz = size[g];
  const int tn = tsize[g];
  int off, toff;
  if (seg_loc) {
    off = seg_loc[g];      // FINAL global offsets (scan fully resolved)
    toff = tgt_loc[g];
  } else {
    off = g * useg;
    toff = g * utgt;
  }

  const int szc = (sz > 0) ? sz : 1;  // clamp for degenerate groups
  const int tnc = (tn > 0) ? tn : 1;

  float4 acc = make_float4(0.f, 0.f, 0.f, 0.f);

  if (sz <= 64 && tn <= 16) {
    // ---- issue ALL index loads first ----
    const int idx = item[off + ((lane < szc) ? lane : (szc - 1))];
    const int tidx = target_item[toff + ((lane < tnc) ? lane : (tnc - 1))];
    const int u = user[off + szc - 1];

    // ---- issue all gathers (segment rows, target rows, user row) ----
    float4 sv[16];
#pragma unroll
    for (int p = 0; p < 16; ++p) {
      const int r = p * 4 + sub;
      const int row = __shfl(idx, (r < szc) ? r : (szc - 1));
      sv[p] = *reinterpret_cast<const float4*>(iw + ((size_t)row << 6) + (c4 << 2));
    }
    float4 tv[4];
#pragma unroll
    for (int p = 0; p < 4; ++p) {
      const int r = p * 4 + sub;
      const int row = __shfl(tidx, (r < tnc) ? r : (tnc - 1));
      tv[p] = *reinterpret_cast<const float4*>(iw + ((size_t)row << 6) + (c4 << 2));
    }
    const float4 ue = *reinterpret_cast<const float4*>(uw + ((size_t)u << 6) + (c4 << 2));

    // ---- segment sum with 0/1 weights (branch-free) ----
#pragma unroll
    for (int p = 0; p < 16; ++p) {
      const int r = p * 4 + sub;
      const float w = (r < sz) ? 1.0f : 0.0f;
      acc.x = fmaf(sv[p].x, w, acc.x);
      acc.y = fmaf(sv[p].y, w, acc.y);
      acc.z = fmaf(sv[p].z, w, acc.z);
      acc.w = fmaf(sv[p].w, w, acc.w);
    }
    acc.x += __shfl_xor(acc.x, 16); acc.y += __shfl_xor(acc.y, 16);
    acc.z += __shfl_xor(acc.z, 16); acc.w += __shfl_xor(acc.w, 16);
    acc.x += __shfl_xor(acc.x, 32); acc.y += __shfl_xor(acc.y, 32);
    acc.z += __shfl_xor(acc.z, 32); acc.w += __shfl_xor(acc.w, 32);

    const float inv_sz = 1.0f / ((float)sz + 1e-6f);
    float4 e;
    e.x = 0.5f * ue.x + 0.5f * (acc.x * inv_sz);
    e.y = 0.5f * ue.y + 0.5f * (acc.y * inv_sz);
    e.z = 0.5f * ue.z + 0.5f * (acc.z * inv_sz);
    e.w = 0.5f * ue.w + 0.5f * (acc.w * inv_sz);

    const float mu = sub16_sum(e.x + e.y + e.z + e.w) * (1.0f / 64.0f);
    e.x -= mu; e.y -= mu; e.z -= mu; e.w -= mu;
    const float ss = sub16_sum(e.x * e.x + e.y * e.y + e.z * e.z + e.w * e.w);
    const float einv = 1.0f / fmaxf(sqrtf(ss), 1e-12f);
    e.x *= einv; e.y *= einv; e.z *= einv; e.w *= einv;

    // ---- 4 independent target reduction chains ----
#pragma unroll
    for (int p = 0; p < 4; ++p) {
      const int r = p * 4 + sub;
      float4 t = tv[p];
      const float tmu = sub16_sum(t.x + t.y + t.z + t.w) * (1.0f / 64.0f);
      t.x -= tmu; t.y -= tmu; t.z -= tmu; t.w -= tmu;
      float tss = t.x * t.x + t.y * t.y + t.z * t.z + t.w * t.w;
      float dt  = e.x * t.x + e.y * t.y + e.z * t.z + e.w * t.w;
      tss = sub16_sum(tss);
      dt  = sub16_sum(dt);
      if (r < tn && c4 == 0) {
        out[toff + r] = dt / fmaxf(sqrtf(tss), 1e-12f);
      }
    }
    return;
  }

  // ---------------- generic fallback (sz > 64 or tn > 16) ----------------
  for (int base = 0; base < sz; base += 64) {
    const int nrem = sz - base;
    const int nchunk = nrem < 64 ? nrem : 64;
    const int idx = (lane < nrem) ? item[off + base + lane] : 0;
#pragma unroll
    for (int i = 0; i < 64; i += 4) {
      const int r = i + sub;
      const int row = __shfl(idx, (r < nchunk) ? r : 0);
      const float w = (r < nchunk) ? 1.0f : 0.0f;
      const float4 v = *reinterpret_cast<const float4*>(iw + ((size_t)row << 6) + (c4 << 2));
      acc.x = fmaf(v.x, w, acc.x);
      acc.y = fmaf(v.y, w, acc.y);
      acc.z = fmaf(v.z, w, acc.z);
      acc.w = fmaf(v.w, w, acc.w);
    }
  }
  acc.x += __shfl_xor(acc.x, 16); acc.y += __shfl_xor(acc.y, 16);
  acc.z += __shfl_xor(acc.z, 16); acc.w += __shfl_xor(acc.w, 16);
  acc.x += __shfl_xor(acc.x, 32); acc.y += __shfl_xor(acc.y, 32);
  acc.z += __shfl_xor(acc.z, 32); acc.w += __shfl_xor(acc.w, 32);

  const float inv_sz = 1.0f / ((float)sz + 1e-6f);
  const int u = user[off + szc - 1];
  const float4 ue = *reinterpret_cast<const float4*>(uw + ((size_t)u << 6) + (c4 << 2));

  float4 e;
  e.x = 0.5f * ue.x + 0.5f * (acc.x * inv_sz);
  e.y = 0.5f * ue.y + 0.5f * (acc.y * inv_sz);
  e.z = 0.5f * ue.z + 0.5f * (acc.z * inv_sz);
  e.w = 0.5f * ue.w + 0.5f * (acc.w * inv_sz);

  const float mu = sub16_sum(e.x + e.y + e.z + e.w) * (1.0f / 64.0f);
  e.x -= mu; e.y -= mu; e.z -= mu; e.w -= mu;
  const float ss = sub16_sum(e.x * e.x + e.y * e.y + e.z * e.z + e.w * e.w);
  const float einv = 1.0f / fmaxf(sqrtf(ss), 1e-12f);
  e.x *= einv; e.y *= einv; e.z *= einv; e.w *= einv;

  for (int tb = 0; tb < tn; tb += 64) {
    const int trem = tn - tb;
    const int tch = trem < 64 ? trem : 64;
    const int tidx = (lane < trem) ? target_item[toff + tb + lane] : 0;
    for (int j = 0; j < tch; j += 4) {
      const int r = j + sub;
      const bool valid = r < tch;
      const int row = __shfl(tidx, valid ? r : 0);
      float4 t = *reinterpret_cast<const float4*>(iw + ((size_t)row << 6) + (c4 << 2));
      const float tmu = sub16_sum(t.x + t.y + t.z + t.w) * (1.0f / 64.0f);
      t.x -= tmu; t.y -= tmu; t.z -= tmu; t.w -= tmu;
      float tss = t.x * t.x + t.y * t.y + t.z * t.z + t.w * t.w;
      float dt  = e.x * t.x + e.y * t.y + e.z * t.z + e.w * t.w;
      tss = sub16_sum(tss);
      dt  = sub16_sum(dt);
      if (valid && c4 == 0) {
        out[toff + tb + r] = dt / fmaxf(sqrtf(tss), 1e-12f);
      }
    }
  }
}

extern "C" void kernel_launch(void* const* d_in, const int* in_sizes, int n_in,
                              void* d_out, int out_size, void* d_ws,
                              size_t ws_size, hipStream_t stream) {
  const int* user        = (const int*)d_in[0];
  const int* item        = (const int*)d_in[1];
  const int* target_item = (const int*)d_in[2];
  const int* size        = (const int*)d_in[3];
  const int* tsize       = (const int*)d_in[4];
  const float* uw        = (const float*)d_in[5];
  const float* iw        = (const float*)d_in[6];
  float* out             = (float*)d_out;

  const int TOTAL = in_sizes[0];
  const int T     = in_sizes[2];
  const int B     = in_sizes[3];
  const int useg  = (B > 0) ? TOTAL / B : 0;  // uniform fallback
  const int utgt  = (B > 0) ? T / B : 0;

  const int nb = (B + 255) >> 8;
  int* seg_loc = nullptr; int* tgt_loc = nullptr;
  int* seg_tot = nullptr; int* tgt_tot = nullptr;
  const size_t need = ((size_t)2 * B + (size_t)2 * nb) * sizeof(int);
  if (ws_size >= need) {
    seg_loc = (int*)d_ws;
    tgt_loc = seg_loc + B;
    seg_tot = tgt_loc + B;
    tgt_tot = seg_tot + nb;
    scan_blocks<<<nb, 256, 0, stream>>>(size, tsize, B, seg_loc, tgt_loc,
                                        seg_tot, tgt_tot);
    if (nb > 1) {
      finalize_scan<<<nb, 256, 0, stream>>>(seg_loc, tgt_loc, seg_tot,
                                            tgt_tot, nb, B);
    }
  }

  const int block = 256;
  const long long threads = (long long)B * 64;
  const int grid = (int)((threads + block - 1) / block);
  simplex_kernel<<<grid, block, 0, stream>>>(user, item, target_item, size,
                                             tsize, uw, iw, seg_loc, tgt_loc,
                                             out, B, useg, utgt);
}

// Round 2
// 440.138 us; speedup vs baseline: 1.0031x; 1.0031x over previous
//
#include <hip/hip_runtime.h>

#define HDIM 64

// 16-lane butterfly sum (subgroup-local: masks 1,2,4,8 stay in bits 0-3).
__device__ __forceinline__ float sub16_sum(float v) {
  v += __shfl_xor(v, 1);
  v += __shfl_xor(v, 2);
  v += __shfl_xor(v, 4);
  v += __shfl_xor(v, 8);
  return v;
}

__device__ __forceinline__ int wave_sum_i(int v) {
  v += __shfl_xor(v, 1);
  v += __shfl_xor(v, 2);
  v += __shfl_xor(v, 4);
  v += __shfl_xor(v, 8);
  v += __shfl_xor(v, 16);
  v += __shfl_xor(v, 32);
  return v;
}

// ---------------------------------------------------------------------------
// Scan pass 1: per-block (256 groups) intra-block exclusive prefix of
// size[]/target_size[] plus per-block totals.
// ---------------------------------------------------------------------------
__global__ __launch_bounds__(256) void scan_blocks(
    const int* __restrict__ size, const int* __restrict__ tsize, int B,
    int* __restrict__ seg_loc, int* __restrict__ tgt_loc,
    int* __restrict__ seg_tot, int* __restrict__ tgt_tot) {
  __shared__ int s1[256];
  __shared__ int s2[256];
  const int t = threadIdx.x;
  const int i = blockIdx.x * 256 + t;
  const int a = (i < B) ? size[i] : 0;
  const int b = (i < B) ? tsize[i] : 0;
  s1[t] = a; s2[t] = b;
  __syncthreads();
#pragma unroll
  for (int d = 1; d < 256; d <<= 1) {
    const int v1 = (t >= d) ? s1[t - d] : 0;
    const int v2 = (t >= d) ? s2[t - d] : 0;
    __syncthreads();
    s1[t] += v1; s2[t] += v2;
    __syncthreads();
  }
  if (i < B) { seg_loc[i] = s1[t] - a; tgt_loc[i] = s2[t] - b; }
  if (t == 255) { seg_tot[blockIdx.x] = s1[255]; tgt_tot[blockIdx.x] = s2[255]; }
}

// ---------------------------------------------------------------------------
// Scan pass 2: add the cross-block base so seg_loc/tgt_loc hold FINAL global
// offsets (hoisted out of the 16384 hot-kernel waves).
// ---------------------------------------------------------------------------
__global__ __launch_bounds__(256) void finalize_scan(
    int* __restrict__ seg_loc, int* __restrict__ tgt_loc,
    const int* __restrict__ seg_tot, const int* __restrict__ tgt_tot,
    int nb, int B) {
  const int bid = blockIdx.x;
  const int lane = threadIdx.x & 63;
  int b1 = 0, b2 = 0;
  for (int s = 0; s < nb; s += 64) {
    const int i = s + lane;
    const bool m = (i < nb) & (i < bid);
    b1 += wave_sum_i(m ? seg_tot[i] : 0);
    b2 += wave_sum_i(m ? tgt_tot[i] : 0);
  }
  const int g = bid * 256 + threadIdx.x;
  if (g < B) { seg_loc[g] += b1; tgt_loc[g] += b2; }
}

// ---------------------------------------------------------------------------
// One wave per group. sub = lane>>4 picks a row slot (4 rows per load pass),
// c4 = lane&15 picks the float4 column quad: each global_load_dwordx4 moves
// 4 full embedding rows (1 KB) coalesced.
// Fast path stages segment rows in TWO batches of 8 float4s (instead of one
// batch of 16) to cut peak VGPR pressure ~32 regs; this allows
// __launch_bounds__(256,4): 16 waves/CU for gather latency hiding (was 12).
// ---------------------------------------------------------------------------
__global__ __launch_bounds__(256, 4) void simplex_kernel(
    const int* __restrict__ user, const int* __restrict__ item,
    const int* __restrict__ target_item, const int* __restrict__ size,
    const int* __restrict__ tsize, const float* __restrict__ uw,
    const float* __restrict__ iw, const int* __restrict__ seg_loc,
    const int* __restrict__ tgt_loc, float* __restrict__ out, int B,
    int useg, int utgt) {
  const int g = (int)((blockIdx.x * blockDim.x + threadIdx.x) >> 6);
  if (g >= B) return;
  const int lane = threadIdx.x & 63;
  const int sub = lane >> 4;
  const int c4 = lane & 15;

  const int sz = size[g];
  const int tn = tsize[g];
  int off, toff;
  if (seg_loc) {
    off = seg_loc[g];      // FINAL global offsets (scan fully resolved)
    toff = tgt_loc[g];
  } else {
    off = g * useg;
    toff = g * utgt;
  }

  const int szc = (sz > 0) ? sz : 1;  // clamp for degenerate groups
  const int tnc = (tn > 0) ? tn : 1;

  float4 acc = make_float4(0.f, 0.f, 0.f, 0.f);

  if (sz <= 64 && tn <= 16) {
    // ---- issue ALL index loads first ----
    const int idx = item[off + ((lane < szc) ? lane : (szc - 1))];
    const int tidx = target_item[toff + ((lane < tnc) ? lane : (tnc - 1))];
    const int u = user[off + szc - 1];

    // ---- batch 1: segment rows 0..31, plus target rows and user row ----
    float4 sv[8];
#pragma unroll
    for (int p = 0; p < 8; ++p) {
      const int r = p * 4 + sub;
      const int row = __shfl(idx, (r < szc) ? r : (szc - 1));
      sv[p] = *reinterpret_cast<const float4*>(iw + ((size_t)row << 6) + (c4 << 2));
    }
    float4 tv[4];
#pragma unroll
    for (int p = 0; p < 4; ++p) {
      const int r = p * 4 + sub;
      const int row = __shfl(tidx, (r < tnc) ? r : (tnc - 1));
      tv[p] = *reinterpret_cast<const float4*>(iw + ((size_t)row << 6) + (c4 << 2));
    }
    const float4 ue = *reinterpret_cast<const float4*>(uw + ((size_t)u << 6) + (c4 << 2));

    // ---- accumulate batch 1 (0/1 weights, branch-free) ----
#pragma unroll
    for (int p = 0; p < 8; ++p) {
      const int r = p * 4 + sub;
      const float w = (r < sz) ? 1.0f : 0.0f;
      acc.x = fmaf(sv[p].x, w, acc.x);
      acc.y = fmaf(sv[p].y, w, acc.y);
      acc.z = fmaf(sv[p].z, w, acc.z);
      acc.w = fmaf(sv[p].w, w, acc.w);
    }

    // ---- batch 2: segment rows 32..63 (reuse sv registers) ----
#pragma unroll
    for (int p = 0; p < 8; ++p) {
      const int r = 32 + p * 4 + sub;
      const int row = __shfl(idx, (r < szc) ? r : (szc - 1));
      sv[p] = *reinterpret_cast<const float4*>(iw + ((size_t)row << 6) + (c4 << 2));
    }
#pragma unroll
    for (int p = 0; p < 8; ++p) {
      const int r = 32 + p * 4 + sub;
      const float w = (r < sz) ? 1.0f : 0.0f;
      acc.x = fmaf(sv[p].x, w, acc.x);
      acc.y = fmaf(sv[p].y, w, acc.y);
      acc.z = fmaf(sv[p].z, w, acc.z);
      acc.w = fmaf(sv[p].w, w, acc.w);
    }

    acc.x += __shfl_xor(acc.x, 16); acc.y += __shfl_xor(acc.y, 16);
    acc.z += __shfl_xor(acc.z, 16); acc.w += __shfl_xor(acc.w, 16);
    acc.x += __shfl_xor(acc.x, 32); acc.y += __shfl_xor(acc.y, 32);
    acc.z += __shfl_xor(acc.z, 32); acc.w += __shfl_xor(acc.w, 32);

    const float inv_sz = 1.0f / ((float)sz + 1e-6f);
    float4 e;
    e.x = 0.5f * ue.x + 0.5f * (acc.x * inv_sz);
    e.y = 0.5f * ue.y + 0.5f * (acc.y * inv_sz);
    e.z = 0.5f * ue.z + 0.5f * (acc.z * inv_sz);
    e.w = 0.5f * ue.w + 0.5f * (acc.w * inv_sz);

    const float mu = sub16_sum(e.x + e.y + e.z + e.w) * (1.0f / 64.0f);
    e.x -= mu; e.y -= mu; e.z -= mu; e.w -= mu;
    const float ss = sub16_sum(e.x * e.x + e.y * e.y + e.z * e.z + e.w * e.w);
    const float einv = 1.0f / fmaxf(sqrtf(ss), 1e-12f);
    e.x *= einv; e.y *= einv; e.z *= einv; e.w *= einv;

    // ---- 4 independent target reduction chains ----
#pragma unroll
    for (int p = 0; p < 4; ++p) {
      const int r = p * 4 + sub;
      float4 t = tv[p];
      const float tmu = sub16_sum(t.x + t.y + t.z + t.w) * (1.0f / 64.0f);
      t.x -= tmu; t.y -= tmu; t.z -= tmu; t.w -= tmu;
      float tss = t.x * t.x + t.y * t.y + t.z * t.z + t.w * t.w;
      float dt  = e.x * t.x + e.y * t.y + e.z * t.z + e.w * t.w;
      tss = sub16_sum(tss);
      dt  = sub16_sum(dt);
      if (r < tn && c4 == 0) {
        out[toff + r] = dt / fmaxf(sqrtf(tss), 1e-12f);
      }
    }
    return;
  }

  // ---------------- generic fallback (sz > 64 or tn > 16) ----------------
  for (int base = 0; base < sz; base += 64) {
    const int nrem = sz - base;
    const int nchunk = nrem < 64 ? nrem : 64;
    const int idx = (lane < nrem) ? item[off + base + lane] : 0;
#pragma unroll
    for (int i = 0; i < 64; i += 4) {
      const int r = i + sub;
      const int row = __shfl(idx, (r < nchunk) ? r : 0);
      const float w = (r < nchunk) ? 1.0f : 0.0f;
      const float4 v = *reinterpret_cast<const float4*>(iw + ((size_t)row << 6) + (c4 << 2));
      acc.x = fmaf(v.x, w, acc.x);
      acc.y = fmaf(v.y, w, acc.y);
      acc.z = fmaf(v.z, w, acc.z);
      acc.w = fmaf(v.w, w, acc.w);
    }
  }
  acc.x += __shfl_xor(acc.x, 16); acc.y += __shfl_xor(acc.y, 16);
  acc.z += __shfl_xor(acc.z, 16); acc.w += __shfl_xor(acc.w, 16);
  acc.x += __shfl_xor(acc.x, 32); acc.y += __shfl_xor(acc.y, 32);
  acc.z += __shfl_xor(acc.z, 32); acc.w += __shfl_xor(acc.w, 32);

  const float inv_sz = 1.0f / ((float)sz + 1e-6f);
  const int u = user[off + szc - 1];
  const float4 ue = *reinterpret_cast<const float4*>(uw + ((size_t)u << 6) + (c4 << 2));

  float4 e;
  e.x = 0.5f * ue.x + 0.5f * (acc.x * inv_sz);
  e.y = 0.5f * ue.y + 0.5f * (acc.y * inv_sz);
  e.z = 0.5f * ue.z + 0.5f * (acc.z * inv_sz);
  e.w = 0.5f * ue.w + 0.5f * (acc.w * inv_sz);

  const float mu = sub16_sum(e.x + e.y + e.z + e.w) * (1.0f / 64.0f);
  e.x -= mu; e.y -= mu; e.z -= mu; e.w -= mu;
  const float ss = sub16_sum(e.x * e.x + e.y * e.y + e.z * e.z + e.w * e.w);
  const float einv = 1.0f / fmaxf(sqrtf(ss), 1e-12f);
  e.x *= einv; e.y *= einv; e.z *= einv; e.w *= einv;

  for (int tb = 0; tb < tn; tb += 64) {
    const int trem = tn - tb;
    const int tch = trem < 64 ? trem : 64;
    const int tidx = (lane < trem) ? target_item[toff + tb + lane] : 0;
    for (int j = 0; j < tch; j += 4) {
      const int r = j + sub;
      const bool valid = r < tch;
      const int row = __shfl(tidx, valid ? r : 0);
      float4 t = *reinterpret_cast<const float4*>(iw + ((size_t)row << 6) + (c4 << 2));
      const float tmu = sub16_sum(t.x + t.y + t.z + t.w) * (1.0f / 64.0f);
      t.x -= tmu; t.y -= tmu; t.z -= tmu; t.w -= tmu;
      float tss = t.x * t.x + t.y * t.y + t.z * t.z + t.w * t.w;
      float dt  = e.x * t.x + e.y * t.y + e.z * t.z + e.w * t.w;
      tss = sub16_sum(tss);
      dt  = sub16_sum(dt);
      if (valid && c4 == 0) {
        out[toff + tb + r] = dt / fmaxf(sqrtf(tss), 1e-12f);
      }
    }
  }
}

extern "C" void kernel_launch(void* const* d_in, const int* in_sizes, int n_in,
                              void* d_out, int out_size, void* d_ws,
                              size_t ws_size, hipStream_t stream) {
  const int* user        = (const int*)d_in[0];
  const int* item        = (const int*)d_in[1];
  const int* target_item = (const int*)d_in[2];
  const int* size        = (const int*)d_in[3];
  const int* tsize       = (const int*)d_in[4];
  const float* uw        = (const float*)d_in[5];
  const float* iw        = (const float*)d_in[6];
  float* out             = (float*)d_out;

  const int TOTAL = in_sizes[0];
  const int T     = in_sizes[2];
  const int B     = in_sizes[3];
  const int useg  = (B > 0) ? TOTAL / B : 0;  // uniform fallback
  const int utgt  = (B > 0) ? T / B : 0;

  const int nb = (B + 255) >> 8;
  int* seg_loc = nullptr; int* tgt_loc = nullptr;
  int* seg_tot = nullptr; int* tgt_tot = nullptr;
  const size_t need = ((size_t)2 * B + (size_t)2 * nb) * sizeof(int);
  if (ws_size >= need) {
    seg_loc = (int*)d_ws;
    tgt_loc = seg_loc + B;
    seg_tot = tgt_loc + B;
    tgt_tot = seg_tot + nb;
    scan_blocks<<<nb, 256, 0, stream>>>(size, tsize, B, seg_loc, tgt_loc,
                                        seg_tot, tgt_tot);
    if (nb > 1) {
      finalize_scan<<<nb, 256, 0, stream>>>(seg_loc, tgt_loc, seg_tot,
                                            tgt_tot, nb, B);
    }
  }

  const int block = 256;
  const long long threads = (long long)B * 64;
  const int grid = (int)((threads + block - 1) / block);
  simplex_kernel<<<grid, block, 0, stream>>>(user, item, target_item, size,
                                             tsize, uw, iw, seg_loc, tgt_loc,
                                             out, B, useg, utgt);
}